// Round 2
// baseline (382.149 us; speedup 1.0000x reference)
//
#include <hip/hip_runtime.h>
#include <stdint.h>

// x [B=32, C=512, H=32, W=32] fp32, 32 groups, S = H*W = 1024. All I/O fp32.
// Internal tensors bf16: xt[b][s][c], qkt[b][s][1024] (q|k fused), v[b][d][s],
// Sc/P[b][s][t] bf16, o_t[b][s][c]. All GEMMs NT (Out[m][n] = sum_k A[m][k]B[n][k])
// on mfma_f32_16x16x32_bf16:
//   A-frag: A[m=lane&15][k=quad*8+j]  B-frag: B[n=lane&15][k=quad*8+j]
//   C/D:    col=lane&15, row=quad*4+reg
// R6: double-buffered BK=32 K-loop, row-pair XOR swizzle (conflict-free, PMC=0),
//     bf16 scores, fused q+k projection. (kernel mfma_nt, kept for v/PV/final)
// R7: bijective XCD-aware block swizzle (T1): scores FETCH 166->49MB, 409->373us.
// R8: 256x256/BK=64 8-wave deep-pipelined kernel (mfma_nt8) for q|k + scores:
//     counted s_waitcnt vmcnt(8) + raw s_barrier (no compiler vmcnt(0) drain),
//     setprio around 32-MFMA clusters, 2 phases/K-tile. LDS layout = 4 sub-blocks
//     of the proven 128x32 row-pair-XOR scheme per 256x64 operand tile.
#define Bsz 32
#define Cch 512
#define Ssp 1024
#define Grp 32
#define CPG 16

typedef unsigned short u16;
typedef __attribute__((ext_vector_type(8))) short bf16x8;
typedef __attribute__((ext_vector_type(4))) float f32x4;

__device__ __forceinline__ float bf2f(u16 u) {
  union { float f; uint32_t i; } w; w.i = ((uint32_t)u) << 16; return w.f;
}
__device__ __forceinline__ u16 f2bf(float f) {
  union { float f; uint32_t i; } w; w.f = f;
  uint32_t r = w.i + 0x7fffu + ((w.i >> 16) & 1u);  // RNE
  return (u16)(r >> 16);
}

__device__ __forceinline__ void gload_lds16(const u16* g, u16* l) {
  __builtin_amdgcn_global_load_lds(
      (const __attribute__((address_space(1))) uint32_t*)g,
      (__attribute__((address_space(3))) uint32_t*)l, 16, 0, 0);
}

// ---------------- GN stats: one block per (b,g) -> per-channel affine (A,B) ----
__global__ __launch_bounds__(256) void gnstats_kernel(
    const float* __restrict__ x, const float* __restrict__ scale,
    const float* __restrict__ bias, float2* __restrict__ stats) {
  int b = blockIdx.x >> 5;
  int g = blockIdx.x & 31;
  size_t base = ((size_t)b * Cch + (size_t)g * CPG) * Ssp;
  const float4* xv = (const float4*)(x + base);

  float sum = 0.f, sumsq = 0.f;
#pragma unroll
  for (int it = 0; it < 16; ++it) {
    float4 v = xv[threadIdx.x + 256 * it];
    sum += (v.x + v.y) + (v.z + v.w);
    sumsq += (v.x * v.x + v.y * v.y) + (v.z * v.z + v.w * v.w);
  }
#pragma unroll
  for (int off = 32; off > 0; off >>= 1) {
    sum += __shfl_xor(sum, off);
    sumsq += __shfl_xor(sumsq, off);
  }
  __shared__ float sm[8];
  int wid = threadIdx.x >> 6;
  if ((threadIdx.x & 63) == 0) { sm[wid] = sum; sm[4 + wid] = sumsq; }
  __syncthreads();
  sum = sm[0] + sm[1] + sm[2] + sm[3];
  sumsq = sm[4] + sm[5] + sm[6] + sm[7];
  float mean = sum * (1.f / 16384.f);
  float var = sumsq * (1.f / 16384.f) - mean * mean;
  float rstd = rsqrtf(var + 1e-6f);
  if (threadIdx.x < CPG) {
    int c = g * CPG + threadIdx.x;
    float sc = scale[c] * rstd;
    stats[(size_t)b * Cch + c] = make_float2(sc, bias[c] - mean * sc);
  }
}

// ---------------- x[b][c][s] fp32 -> xt[b][s][c] bf16 with GN affine ----------
__global__ __launch_bounds__(256) void xpose_gn(
    const float* __restrict__ x, const float2* __restrict__ stats,
    u16* __restrict__ xt) {
  __shared__ float T[64][65];
  int b = blockIdx.z;
  int s0 = blockIdx.x * 64, c0 = blockIdx.y * 64;
  int t = threadIdx.x;
  {
    int tx = t & 15, ty = t >> 4;
    const float* xb = x + ((size_t)b * Cch + c0) * Ssp + s0;
#pragma unroll
    for (int i = 0; i < 4; ++i) {
      int c = ty + 16 * i;
      float2 af = stats[(size_t)b * Cch + c0 + c];
      float4 v = *(const float4*)&xb[(size_t)c * Ssp + tx * 4];
      T[c][tx * 4 + 0] = v.x * af.x + af.y;
      T[c][tx * 4 + 1] = v.y * af.x + af.y;
      T[c][tx * 4 + 2] = v.z * af.x + af.y;
      T[c][tx * 4 + 3] = v.w * af.x + af.y;
    }
  }
  __syncthreads();
  {
    int cx = t & 7, sy = t >> 3;
    u16* ob = xt + ((size_t)b * Ssp + s0) * Cch + c0;
#pragma unroll
    for (int i = 0; i < 2; ++i) {
      int s = sy + 32 * i;
      union { u16 h[8]; uint4 v4; } pk;
#pragma unroll
      for (int j = 0; j < 8; ++j) pk.h[j] = f2bf(T[cx * 8 + j][s]);
      *(uint4*)&ob[(size_t)s * Cch + cx * 8] = pk.v4;
    }
  }
}

// ---------------- W[c][d] fp32 (512x512) -> Wt[d][c] bf16, 4 weights ----------
__global__ __launch_bounds__(256) void wxpose(
    const float* __restrict__ w0, const float* __restrict__ w1,
    const float* __restrict__ w2, const float* __restrict__ w3,
    u16* __restrict__ dst) {
  const float* W = blockIdx.z == 0 ? w0 : blockIdx.z == 1 ? w1
                   : blockIdx.z == 2 ? w2 : w3;
  u16* D = dst + (size_t)blockIdx.z * Cch * Cch;
  __shared__ float T[64][65];
  int d0 = blockIdx.x * 64, c0 = blockIdx.y * 64;
  int t = threadIdx.x;
  {
    int tx = t & 15, ty = t >> 4;
#pragma unroll
    for (int i = 0; i < 4; ++i) {
      int c = ty + 16 * i;
      float4 v = *(const float4*)&W[(size_t)(c0 + c) * Cch + d0 + tx * 4];
      T[c][tx * 4 + 0] = v.x; T[c][tx * 4 + 1] = v.y;
      T[c][tx * 4 + 2] = v.z; T[c][tx * 4 + 3] = v.w;
    }
  }
  __syncthreads();
  {
    int cx = t & 7, dy = t >> 3;
#pragma unroll
    for (int i = 0; i < 2; ++i) {
      int d = dy + 32 * i;
      union { u16 h[8]; uint4 v4; } pk;
#pragma unroll
      for (int j = 0; j < 8; ++j) pk.h[j] = f2bf(T[cx * 8 + j][d]);
      *(uint4*)&D[(size_t)(d0 + d) * Cch + c0 + cx * 8] = pk.v4;
    }
  }
}

// ---------------- Unified MFMA NT GEMM, double-buffered BK=32 (2-phase) -------
// 128x128 tile, 4 waves in 2x2 of 64x64, 4x4 16x16x32 MFMA tiles/wave.
// Kept for v-proj (EPI 1), PV (EPI 3), final (EPI 4).
template <int EPI>
__global__ __launch_bounds__(256) void mfma_nt(
    const u16* __restrict__ A, size_t sAb, int lda,
    const u16* __restrict__ B, size_t sBb, int ldb,
    void* __restrict__ Out, size_t sOb, int ldo,
    const float* __restrict__ bias,
    const float* __restrict__ bias2_or_resid, size_t sRb, int K) {
  __shared__ u16 As[2 * 4096];
  __shared__ u16 Bs[2 * 4096];

  // bijective XCD-aware swizzle (R7)
  const int nx = gridDim.x, ny = gridDim.y;
  const int pb = nx * ny;
  const int nwg = pb * gridDim.z;
  const int flat = (blockIdx.z * ny + blockIdx.y) * nx + blockIdx.x;
  const int qq = nwg >> 3, rr = nwg & 7;
  const int xcd = flat & 7, lid = flat >> 3;
  const int nf = (xcd < rr ? xcd * (qq + 1) : rr * (qq + 1) + (xcd - rr) * qq) + lid;
  const int b = nf / pb;
  const int rem = nf - b * pb;
  const int m0 = (rem / nx) * 128, n0 = (rem % nx) * 128;

  const int tid = threadIdx.x;
  const int lane = tid & 63, wave = tid >> 6;
  const int wm = wave >> 1, wn = wave & 1;
  const int quad = lane >> 4, l16 = lane & 15;

  const int sp = lane & 7, sq = lane >> 3;
  const int scl = sp ^ sq;
  const int srow = 2 * sq + (scl >> 2);
  const int scol = (scl & 3) * 8;

  const u16* Ab = A + (size_t)b * sAb + (size_t)m0 * lda;
  const u16* Bb = B + (size_t)b * sBb + (size_t)n0 * ldb;

  f32x4 acc[4][4] = {};

#define STAGE(bufidx, kk)                                                      \
  {                                                                            \
    _Pragma("unroll") for (int i = 0; i < 2; ++i) {                            \
      int seg = 2 * wave + i;                                                  \
      gload_lds16(Ab + (size_t)(16 * seg + srow) * lda + (kk) + scol,          \
                  As + (bufidx) * 4096 + seg * 512);                           \
      gload_lds16(Bb + (size_t)(16 * seg + srow) * ldb + (kk) + scol,          \
                  Bs + (bufidx) * 4096 + seg * 512);                           \
    }                                                                          \
  }

  STAGE(0, 0)
  __syncthreads();
  int cur = 0;
  for (int k0 = 0; k0 < K; k0 += 32) {
    if (k0 + 32 < K) STAGE(cur ^ 1, k0 + 32)
    bf16x8 af[4], bfr[4];
#pragma unroll
    for (int i = 0; i < 4; ++i) {
      int ra = wm * 64 + i * 16 + l16;
      int qa = ra >> 1, ca = ((ra & 1) << 2) + quad;
      af[i] = *(const bf16x8*)&As[cur * 4096 + qa * 64 + (ca ^ (qa & 7)) * 8];
      int rb = wn * 64 + i * 16 + l16;
      int qb = rb >> 1, cb = ((rb & 1) << 2) + quad;
      bfr[i] = *(const bf16x8*)&Bs[cur * 4096 + qb * 64 + (cb ^ (qb & 7)) * 8];
    }
#pragma unroll
    for (int mt = 0; mt < 4; ++mt)
#pragma unroll
      for (int nt = 0; nt < 4; ++nt)
        acc[mt][nt] = __builtin_amdgcn_mfma_f32_16x16x32_bf16(
            af[mt], bfr[nt], acc[mt][nt], 0, 0, 0);
    __syncthreads();
    cur ^= 1;
  }
#undef STAGE

  const float SCALE = 0.044194173824159216f;  // 512^-0.5
#pragma unroll
  for (int mt = 0; mt < 4; ++mt) {
#pragma unroll
    for (int nt = 0; nt < 4; ++nt) {
      int n = n0 + wn * 64 + nt * 16 + l16;
      float bn = 0.f;
      if constexpr (EPI == 0)
        bn = (n < 512) ? bias[n] : bias2_or_resid[n - 512];
#pragma unroll
      for (int reg = 0; reg < 4; ++reg) {
        int m = m0 + wm * 64 + mt * 16 + quad * 4 + reg;
        float v = acc[mt][nt][reg];
        size_t idx = (size_t)b * sOb + (size_t)m * ldo + n;
        if constexpr (EPI == 0) {
          ((u16*)Out)[idx] = f2bf(v + bn);
        } else if constexpr (EPI == 1) {
          ((u16*)Out)[idx] = f2bf(v + bias[m]);
        } else if constexpr (EPI == 2) {
          ((u16*)Out)[idx] = f2bf(v * SCALE);
        } else if constexpr (EPI == 3) {
          ((u16*)Out)[idx] = f2bf(v);
        } else {
          ((float*)Out)[idx] =
              v + bias[m] + bias2_or_resid[(size_t)b * sRb + (size_t)m * ldo + n];
        }
      }
    }
  }
}

// ---------------- R8: 256x256 BK=64 8-wave deep-pipelined NT GEMM -------------
// 8 waves in 2(M)x4(N); per-wave output 128x64 = 8 m-frags x 4 n-frags.
// LDS: per operand 2 buffers x 32KB; a 256x64 K-tile = 4 sub-blocks
// (row-half h, k-half kh), each the proven 128x32 row-pair-XOR layout:
//   within sub-block: pair-line q = r'>>1 holds rows {2q,2q+1}; logical chunk
//   c = (r'&1)*4 + k'/8; physical chunk p = c ^ (q&7). 2-way max on reads.
// K-loop: STAGE(next: 8 gload_lds/thread) -> s_waitcnt vmcnt(8) -> raw
// s_barrier (NO __syncthreads => no compiler vmcnt(0) drain: next tile's loads
// stay in flight across the whole compute span) -> 2 phases x {ds_read frags,
// setprio(1), 32 MFMA, setprio(0), raw barrier}.
// EPI 0: bf16 out + bias (n<512: bias[n], else bias2[n-512])  (fused q|k)
// EPI 2: bf16 out * C^-0.5                                    (scores)
template <int EPI>
__global__ __launch_bounds__(512, 2) void mfma_nt8(
    const u16* __restrict__ A, size_t sAb, int lda,
    const u16* __restrict__ B, size_t sBb, int ldb,
    void* __restrict__ Out, size_t sOb, int ldo,
    const float* __restrict__ bias,
    const float* __restrict__ bias2, int K) {
  __shared__ u16 As[2 * 16384];  // 64 KB
  __shared__ u16 Bs[2 * 16384];  // 64 KB

  // bijective XCD-aware swizzle (R7)
  const int nx = gridDim.x, ny = gridDim.y;
  const int pb = nx * ny;
  const int nwg = pb * gridDim.z;
  const int flat = (blockIdx.z * ny + blockIdx.y) * nx + blockIdx.x;
  const int qq = nwg >> 3, rr = nwg & 7;
  const int xcd = flat & 7, lid = flat >> 3;
  const int nf = (xcd < rr ? xcd * (qq + 1) : rr * (qq + 1) + (xcd - rr) * qq) + lid;
  const int b = nf / pb;
  const int rem = nf - b * pb;
  const int m0 = (rem / nx) * 256, n0 = (rem % nx) * 256;

  const int tid = threadIdx.x;
  const int lane = tid & 63, wave = tid >> 6;   // wave 0..7
  const int wm = wave >> 2, wn = wave & 3;      // 2 x 4 wave grid
  const int quad = lane >> 4, l16 = lane & 15;

  // staging decode (identical to proven scheme, per 16-row segment)
  const int sp = lane & 7, sq = lane >> 3;
  const int scl = sp ^ sq;
  const int srow = 2 * sq + (scl >> 2);
  const int scol = (scl & 3) * 8;

  // per-lane variable part of all fragment LDS offsets (elements):
  //   q&7 = l16>>1 within every sub-block; p = ((l16&1)*4 + quad) ^ (l16>>1)
  const int vbase = ((l16 >> 1) << 6) + ((((l16 & 1) << 2) | quad) ^ (l16 >> 1)) * 8;
  const int aw = wm * 8192;                         // A row-half = wm
  const int bw = (wn >> 1) * 8192 + (wn & 1) * 2048;  // B row-half/quarter by wn

  const u16* Ab = A + (size_t)b * sAb + (size_t)m0 * lda;
  const u16* Bb = B + (size_t)b * sBb + (size_t)n0 * ldb;

  f32x4 acc[8][4] = {};

  // stage one 256x64 K-tile per operand: 32 segments each (sub=gs>>3: row-half
  // gs>>4, k-half (gs>>3)&1; seg=gs&7). wave w stages gs in [4w, 4w+4).
  // 8 gload_lds / thread / STAGE.
#define STAGE8(bufidx, kt)                                                     \
  {                                                                            \
    _Pragma("unroll") for (int i = 0; i < 4; ++i) {                            \
      int gs = wave * 4 + i;                                                   \
      int row = ((gs >> 4) << 7) + ((gs & 7) << 4) + srow;                     \
      int kof = (kt) * 64 + (((gs >> 3) & 1) << 5) + scol;                     \
      gload_lds16(Ab + (size_t)row * lda + kof,                                \
                  As + (bufidx) * 16384 + gs * 512);                           \
      gload_lds16(Bb + (size_t)row * ldb + kof,                                \
                  Bs + (bufidx) * 16384 + gs * 512);                           \
    }                                                                          \
  }

  STAGE8(0, 0)
  asm volatile("s_waitcnt vmcnt(0)" ::: "memory");
  asm volatile("s_barrier" ::: "memory");

  const int nk = K >> 6;
  for (int kt = 0; kt < nk; ++kt) {
    const int cur = kt & 1;
    if (kt + 1 < nk) {
      STAGE8(cur ^ 1, kt + 1)  // 8 new loads; tile kt's 8 are older
      asm volatile("s_waitcnt vmcnt(8)" ::: "memory");  // tile kt landed
    } else {
      asm volatile("s_waitcnt vmcnt(0)" ::: "memory");
    }
    asm volatile("s_barrier" ::: "memory");  // tile kt visible to all waves

    bf16x8 bfv[4][2], af[4][2];
    // phase 0: all B frags + A m-frags 0..3
#pragma unroll
    for (int nfr = 0; nfr < 4; ++nfr)
#pragma unroll
      for (int kr = 0; kr < 2; ++kr)
        bfv[nfr][kr] = *(const bf16x8*)&Bs[cur * 16384 + bw + kr * 4096 +
                                           nfr * 512 + vbase];
#pragma unroll
    for (int mf = 0; mf < 4; ++mf)
#pragma unroll
      for (int kr = 0; kr < 2; ++kr)
        af[mf][kr] = *(const bf16x8*)&As[cur * 16384 + aw + kr * 4096 +
                                         mf * 512 + vbase];
    __builtin_amdgcn_s_setprio(1);
#pragma unroll
    for (int mf = 0; mf < 4; ++mf)
#pragma unroll
      for (int nfr = 0; nfr < 4; ++nfr)
#pragma unroll
        for (int kr = 0; kr < 2; ++kr)
          acc[mf][nfr] = __builtin_amdgcn_mfma_f32_16x16x32_bf16(
              af[mf][kr], bfv[nfr][kr], acc[mf][nfr], 0, 0, 0);
    __builtin_amdgcn_s_setprio(0);
    asm volatile("s_barrier" ::: "memory");
    // phase 1: A m-frags 4..7 (B stays live)
#pragma unroll
    for (int mf = 0; mf < 4; ++mf)
#pragma unroll
      for (int kr = 0; kr < 2; ++kr)
        af[mf][kr] = *(const bf16x8*)&As[cur * 16384 + aw + kr * 4096 +
                                         (4 + mf) * 512 + vbase];
    __builtin_amdgcn_s_setprio(1);
#pragma unroll
    for (int mf = 0; mf < 4; ++mf)
#pragma unroll
      for (int nfr = 0; nfr < 4; ++nfr)
#pragma unroll
        for (int kr = 0; kr < 2; ++kr)
          acc[4 + mf][nfr] = __builtin_amdgcn_mfma_f32_16x16x32_bf16(
              af[mf][kr], bfv[nfr][kr], acc[4 + mf][nfr], 0, 0, 0);
    __builtin_amdgcn_s_setprio(0);
    // end-of-tile: all waves done reading buf `cur` before next STAGE overwrites
    asm volatile("s_barrier" ::: "memory");
  }
#undef STAGE8

  const float SCALE = 0.044194173824159216f;  // 512^-0.5
#pragma unroll
  for (int mf = 0; mf < 8; ++mf) {
#pragma unroll
    for (int nfr = 0; nfr < 4; ++nfr) {
      int n = n0 + wn * 64 + nfr * 16 + l16;
      float bn = 0.f;
      if constexpr (EPI == 0) bn = (n < 512) ? bias[n] : bias2[n - 512];
#pragma unroll
      for (int reg = 0; reg < 4; ++reg) {
        int m = m0 + wm * 128 + mf * 16 + quad * 4 + reg;
        float v = acc[mf][nfr][reg];
        size_t idx = (size_t)b * sOb + (size_t)m * ldo + n;
        if constexpr (EPI == 0) {
          ((u16*)Out)[idx] = f2bf(v + bn);
        } else {
          ((u16*)Out)[idx] = f2bf(v * SCALE);
        }
      }
    }
  }
}

// ---------------- Softmax over bf16 rows of Sc [nb*S][S], in place ------------
__global__ __launch_bounds__(256) void softmax_kernel(u16* __restrict__ Sc) {
  size_t row = blockIdx.x;
  u16* rp = Sc + row * (size_t)Ssp;
  uint2 u = ((const uint2*)rp)[threadIdx.x];  // 4 bf16
  const u16* ph = (const u16*)&u;
  float v0 = bf2f(ph[0]), v1 = bf2f(ph[1]), v2 = bf2f(ph[2]), v3 = bf2f(ph[3]);
  float mx = fmaxf(fmaxf(v0, v1), fmaxf(v2, v3));
#pragma unroll
  for (int off = 32; off > 0; off >>= 1) mx = fmaxf(mx, __shfl_xor(mx, off));
  __shared__ float sm[4];
  __shared__ float sd[4];
  int wid = threadIdx.x >> 6;
  if ((threadIdx.x & 63) == 0) sm[wid] = mx;
  __syncthreads();  // also: all row reads complete before any write below
  mx = fmaxf(fmaxf(sm[0], sm[1]), fmaxf(sm[2], sm[3]));
  float e0 = __expf(v0 - mx), e1 = __expf(v1 - mx);
  float e2 = __expf(v2 - mx), e3 = __expf(v3 - mx);
  float s = e0 + e1 + e2 + e3;
#pragma unroll
  for (int off = 32; off > 0; off >>= 1) s += __shfl_xor(s, off);
  if ((threadIdx.x & 63) == 0) sd[wid] = s;
  __syncthreads();
  s = sd[0] + sd[1] + sd[2] + sd[3];
  float inv = 1.f / s;
  union { u16 s4[4]; uint2 v2; } pk;
  pk.s4[0] = f2bf(e0 * inv); pk.s4[1] = f2bf(e1 * inv);
  pk.s4[2] = f2bf(e2 * inv); pk.s4[3] = f2bf(e3 * inv);
  ((uint2*)rp)[threadIdx.x] = pk.v2;
}

extern "C" void kernel_launch(void* const* d_in, const int* in_sizes, int n_in,
                              void* d_out, int out_size, void* d_ws, size_t ws_size,
                              hipStream_t stream) {
  (void)in_sizes; (void)n_in; (void)out_size;
  const float* x   = (const float*)d_in[0];
  const float* gns = (const float*)d_in[1];
  const float* gnb = (const float*)d_in[2];
  const float* Wq  = (const float*)d_in[3];
  const float* bq  = (const float*)d_in[4];
  const float* Wk  = (const float*)d_in[5];
  const float* bk  = (const float*)d_in[6];
  const float* Wv  = (const float*)d_in[7];
  const float* bv  = (const float*)d_in[8];
  const float* Wt  = (const float*)d_in[9];
  const float* bt  = (const float*)d_in[10];
  float* out = (float*)d_out;
  char* ws = (char*)d_ws;

  // Workspace:
  //   qkt @ 0MB   (64MB bf16 [b][s][1024], q|k fused) -> o_t aliases its start
  //   v   @ 64MB  (32MB bf16 [b][d][s])
  //   W_t @ 96MB  (4 x 0.5MB bf16 [d][c]: q,k,v,t -> Wq|Wk contiguous = fused N)
  //   stats @98MB (256KB float2)
  //   xt  @ 99MB  (32MB bf16 [b][s][c]) -> dead after projections
  //   Sc  @ 99MB  (NB*2MB bf16, overlays xt; softmax in place)
  const size_t QKSZ = (size_t)Bsz * Ssp * 1024 * 2;  // 64 MB
  u16* qkt = (u16*)ws;
  u16* vv  = (u16*)(ws + QKSZ);
  u16* Wts = (u16*)(ws + (96ull << 20));
  float2* stats = (float2*)(ws + (98ull << 20));
  u16* xt  = (u16*)(ws + (99ull << 20));
  u16* Sc  = xt;
  u16* ot  = qkt;

  int NB;  // batches per score chunk (Sc = NB*2MB @ 99MB); ws_size is constant
  if (ws_size >= (163ull << 20)) NB = 32;
  else if (ws_size >= (131ull << 20)) NB = 16;
  else NB = 8;

  const size_t WSZ = (size_t)Cch * Cch;
  u16* Wvt = Wts + 2 * WSZ;
  u16* Wtt = Wts + 3 * WSZ;

  const size_t sSC  = (size_t)Ssp * Cch;   // xt / o_t per-batch elems
  const size_t sQK  = (size_t)Ssp * 1024;  // qkt per-batch elems
  const size_t sCS  = (size_t)Cch * Ssp;   // v / x / out per-batch elems
  const size_t sScB = (size_t)Ssp * Ssp;   // score per-batch elems (bf16)
  dim3 blk(256);
  dim3 blk8(512);

  gnstats_kernel<<<dim3(Bsz * Grp), blk, 0, stream>>>(x, gns, gnb, stats);
  xpose_gn<<<dim3(Ssp / 64, Cch / 64, Bsz), blk, 0, stream>>>(x, stats, xt);
  wxpose<<<dim3(8, 8, 4), blk, 0, stream>>>(Wq, Wk, Wv, Wt, Wts);

  // fused q|k: m=s(1024), n=dq|dk(1024), k=c(512): A=xt, B=Wq_t|Wk_t (256^2 tiles)
  mfma_nt8<0><<<dim3(4, 4, Bsz), blk8, 0, stream>>>(
      xt, sSC, Cch, Wts, 0, Cch, qkt, sQK, 1024, bq, bk, Cch);
  // v: m=d(512), n=s(1024), k=c(512): A=Wv_t, B=xt -> v[d][s] + bias[m]
  mfma_nt<1><<<dim3(8, 4, Bsz), blk, 0, stream>>>(
      Wvt, 0, Cch, xt, sSC, Cch, vv, sCS, Ssp, bv, nullptr, 0, Cch);

  for (int b0 = 0; b0 < Bsz; b0 += NB) {
    int nb = (b0 + NB <= Bsz) ? NB : (Bsz - b0);
    // scores: m=s, n=s', k=d: A=q (qkt+0), B=k (qkt+512) -> Sc bf16 * C^-0.5
    mfma_nt8<2><<<dim3(4, 4, nb), blk8, 0, stream>>>(
        qkt + b0 * sQK, sQK, 1024, qkt + b0 * sQK + 512, sQK, 1024,
        Sc, sScB, Ssp, nullptr, nullptr, Cch);
    softmax_kernel<<<dim3(nb * Ssp), blk, 0, stream>>>(Sc);
    // PV: m=s(1024), n=c(512), k=t(1024): A=P bf16, B=v -> o_t[s][c]
    mfma_nt<3><<<dim3(4, 8, nb), blk, 0, stream>>>(
        Sc, sScB, Ssp, vv + b0 * sCS, sCS, Ssp,
        ot + b0 * sSC, sSC, Cch, nullptr, nullptr, 0, Ssp);
  }

  // final: m=d(512), n=s(1024), k=c(512): A=Wt_t, B=o_t -> fp32 +bias[m]+x
  mfma_nt<4><<<dim3(8, 4, Bsz), blk, 0, stream>>>(
      Wtt, 0, Cch, ot, sSC, Cch, out, sCS, Ssp, bt, x, sCS, Cch);
}

// Round 3
// 358.737 us; speedup vs baseline: 1.0653x; 1.0653x over previous
//
#include <hip/hip_runtime.h>
#include <stdint.h>

// x [B=32, C=512, H=32, W=32] fp32, 32 groups, S = H*W = 1024. All I/O fp32.
// Internal tensors bf16: xt[b][s][c], qkt[b][s][1024] (q|k fused), v[b][d][s],
// Sc/P[b][s][t] bf16, o_t[b][s][c]. All GEMMs NT (Out[m][n] = sum_k A[m][k]B[n][k])
// on mfma_f32_16x16x32_bf16:
//   A-frag: A[m=lane&15][k=quad*8+j]  B-frag: B[n=lane&15][k=quad*8+j]
//   C/D:    col=lane&15, row=quad*4+reg
// R7: bijective XCD-aware block swizzle (T1): scores FETCH 166->49MB.
// R9: one unified GEMM kernel mfma_nt3 for all 5 GEMMs:
//     256x128 tile, 8 waves (4M x 2N), acc 64 regs/wave -> launch_bounds(512,4)
//     => 2 blocks/CU (cross-block TLP) AND BK=32 TRIPLE-buffered LDS (72KB)
//     with prefetch depth 2, counted s_waitcnt vmcnt(6) + raw s_barrier
//     (no compiler vmcnt(0) drain), setprio around MFMA cluster.
//     R2 lesson: 256^2/8-wave held 240 regs/wave -> 1 block/CU -> no TLP ->
//     no gain; this config buys pipeline depth AND a co-resident block.
#define Bsz 32
#define Cch 512
#define Ssp 1024
#define Grp 32
#define CPG 16

typedef unsigned short u16;
typedef __attribute__((ext_vector_type(8))) short bf16x8;
typedef __attribute__((ext_vector_type(4))) float f32x4;

__device__ __forceinline__ float bf2f(u16 u) {
  union { float f; uint32_t i; } w; w.i = ((uint32_t)u) << 16; return w.f;
}
__device__ __forceinline__ u16 f2bf(float f) {
  union { float f; uint32_t i; } w; w.f = f;
  uint32_t r = w.i + 0x7fffu + ((w.i >> 16) & 1u);  // RNE
  return (u16)(r >> 16);
}

__device__ __forceinline__ void gload_lds16(const u16* g, u16* l) {
  __builtin_amdgcn_global_load_lds(
      (const __attribute__((address_space(1))) uint32_t*)g,
      (__attribute__((address_space(3))) uint32_t*)l, 16, 0, 0);
}

// ---------------- GN stats: one block per (b,g) -> per-channel affine (A,B) ----
__global__ __launch_bounds__(256) void gnstats_kernel(
    const float* __restrict__ x, const float* __restrict__ scale,
    const float* __restrict__ bias, float2* __restrict__ stats) {
  int b = blockIdx.x >> 5;
  int g = blockIdx.x & 31;
  size_t base = ((size_t)b * Cch + (size_t)g * CPG) * Ssp;
  const float4* xv = (const float4*)(x + base);

  float sum = 0.f, sumsq = 0.f;
#pragma unroll
  for (int it = 0; it < 16; ++it) {
    float4 v = xv[threadIdx.x + 256 * it];
    sum += (v.x + v.y) + (v.z + v.w);
    sumsq += (v.x * v.x + v.y * v.y) + (v.z * v.z + v.w * v.w);
  }
#pragma unroll
  for (int off = 32; off > 0; off >>= 1) {
    sum += __shfl_xor(sum, off);
    sumsq += __shfl_xor(sumsq, off);
  }
  __shared__ float sm[8];
  int wid = threadIdx.x >> 6;
  if ((threadIdx.x & 63) == 0) { sm[wid] = sum; sm[4 + wid] = sumsq; }
  __syncthreads();
  sum = sm[0] + sm[1] + sm[2] + sm[3];
  sumsq = sm[4] + sm[5] + sm[6] + sm[7];
  float mean = sum * (1.f / 16384.f);
  float var = sumsq * (1.f / 16384.f) - mean * mean;
  float rstd = rsqrtf(var + 1e-6f);
  if (threadIdx.x < CPG) {
    int c = g * CPG + threadIdx.x;
    float sc = scale[c] * rstd;
    stats[(size_t)b * Cch + c] = make_float2(sc, bias[c] - mean * sc);
  }
}

// ---------------- x[b][c][s] fp32 -> xt[b][s][c] bf16 with GN affine ----------
__global__ __launch_bounds__(256) void xpose_gn(
    const float* __restrict__ x, const float2* __restrict__ stats,
    u16* __restrict__ xt) {
  __shared__ float T[64][65];
  int b = blockIdx.z;
  int s0 = blockIdx.x * 64, c0 = blockIdx.y * 64;
  int t = threadIdx.x;
  {
    int tx = t & 15, ty = t >> 4;
    const float* xb = x + ((size_t)b * Cch + c0) * Ssp + s0;
#pragma unroll
    for (int i = 0; i < 4; ++i) {
      int c = ty + 16 * i;
      float2 af = stats[(size_t)b * Cch + c0 + c];
      float4 v = *(const float4*)&xb[(size_t)c * Ssp + tx * 4];
      T[c][tx * 4 + 0] = v.x * af.x + af.y;
      T[c][tx * 4 + 1] = v.y * af.x + af.y;
      T[c][tx * 4 + 2] = v.z * af.x + af.y;
      T[c][tx * 4 + 3] = v.w * af.x + af.y;
    }
  }
  __syncthreads();
  {
    int cx = t & 7, sy = t >> 3;
    u16* ob = xt + ((size_t)b * Ssp + s0) * Cch + c0;
#pragma unroll
    for (int i = 0; i < 2; ++i) {
      int s = sy + 32 * i;
      union { u16 h[8]; uint4 v4; } pk;
#pragma unroll
      for (int j = 0; j < 8; ++j) pk.h[j] = f2bf(T[cx * 8 + j][s]);
      *(uint4*)&ob[(size_t)s * Cch + cx * 8] = pk.v4;
    }
  }
}

// ---------------- W[c][d] fp32 (512x512) -> Wt[d][c] bf16, 4 weights ----------
__global__ __launch_bounds__(256) void wxpose(
    const float* __restrict__ w0, const float* __restrict__ w1,
    const float* __restrict__ w2, const float* __restrict__ w3,
    u16* __restrict__ dst) {
  const float* W = blockIdx.z == 0 ? w0 : blockIdx.z == 1 ? w1
                   : blockIdx.z == 2 ? w2 : w3;
  u16* D = dst + (size_t)blockIdx.z * Cch * Cch;
  __shared__ float T[64][65];
  int d0 = blockIdx.x * 64, c0 = blockIdx.y * 64;
  int t = threadIdx.x;
  {
    int tx = t & 15, ty = t >> 4;
#pragma unroll
    for (int i = 0; i < 4; ++i) {
      int c = ty + 16 * i;
      float4 v = *(const float4*)&W[(size_t)(c0 + c) * Cch + d0 + tx * 4];
      T[c][tx * 4 + 0] = v.x; T[c][tx * 4 + 1] = v.y;
      T[c][tx * 4 + 2] = v.z; T[c][tx * 4 + 3] = v.w;
    }
  }
  __syncthreads();
  {
    int cx = t & 7, dy = t >> 3;
#pragma unroll
    for (int i = 0; i < 2; ++i) {
      int d = dy + 32 * i;
      union { u16 h[8]; uint4 v4; } pk;
#pragma unroll
      for (int j = 0; j < 8; ++j) pk.h[j] = f2bf(T[cx * 8 + j][d]);
      *(uint4*)&D[(size_t)(d0 + d) * Cch + c0 + cx * 8] = pk.v4;
    }
  }
}

// ---------------- R9: 256x128 BK=32 8-wave triple-buffered NT GEMM ------------
// 8 waves in 4(M)x2(N); per-wave output 64x64 = 4 m-frags x 4 n-frags (16 accs).
// LDS: A 3 bufs x 16KB (256x32), B 3 bufs x 8KB (128x32); each operand tile =
// sub-blocks of the proven 128x32 row-pair-XOR layout (pair-line q = rows
// {2q,2q+1}; logical chunk c = (r&1)*4 + k/8; physical p = c ^ (q&7)).
// K-loop iter kt: STAGE(kt+2) [3 gload_lds/thread] -> s_waitcnt vmcnt(6)
// [tile kt landed, tiles kt+1/kt+2 in flight] -> s_barrier -> ds_read frags,
// setprio(1), 16 MFMA, setprio(0) -> s_barrier. Raw barriers: no vmcnt(0) drain.
// EPI 0: bf16 out + bias (n<512: bias[n], else b2[n-512])  (fused q|k proj)
// EPI 1: bf16 out + bias[m]                                (v proj -> v[d][s])
// EPI 2: bf16 out * C^-0.5                                 (scores -> Sc bf16)
// EPI 3: bf16 out                                          (PV -> o_t[s][c])
// EPI 4: f32 out + bias[m] + resid                         (final -> out[d][s])
template <int EPI>
__global__ __launch_bounds__(512, 4) void mfma_nt3(
    const u16* __restrict__ A, size_t sAb, int lda,
    const u16* __restrict__ B, size_t sBb, int ldb,
    void* __restrict__ Out, size_t sOb, int ldo,
    const float* __restrict__ bias,
    const float* __restrict__ bias2_or_resid, size_t sRb, int K) {
  __shared__ u16 As[3 * 8192];  // 48 KB
  __shared__ u16 Bs[3 * 4096];  // 24 KB

  // bijective XCD-aware swizzle (R7)
  const int nx = gridDim.x, ny = gridDim.y;
  const int pb = nx * ny;
  const int nwg = pb * gridDim.z;
  const int flat = (blockIdx.z * ny + blockIdx.y) * nx + blockIdx.x;
  const int qq = nwg >> 3, rr = nwg & 7;
  const int xcd = flat & 7, lid = flat >> 3;
  const int nf = (xcd < rr ? xcd * (qq + 1) : rr * (qq + 1) + (xcd - rr) * qq) + lid;
  const int b = nf / pb;
  const int rem = nf - b * pb;
  const int m0 = (rem / nx) * 256, n0 = (rem % nx) * 128;

  const int tid = threadIdx.x;
  const int lane = tid & 63, wave = tid >> 6;  // wave 0..7
  const int wm = wave >> 1, wn = wave & 1;     // 4(M) x 2(N) wave grid
  const int quad = lane >> 4, l16 = lane & 15;

  // staging decode (proven): phys chunk p = lane&7 of pair q' = lane>>3 within
  // a 16-row segment; logical c = p ^ q' -> row 2q' + (c>>2), k-off (c&3)*8.
  const int sp = lane & 7, sq = lane >> 3;
  const int scl = sp ^ sq;
  const int srow = 2 * sq + (scl >> 2);
  const int scol = (scl & 3) * 8;

  // fragment-read per-lane offset within a 16-row/512-elem segment
  const int vbase =
      ((l16 >> 1) << 6) + ((((l16 & 1) << 2) | quad) ^ (l16 >> 1)) * 8;

  const u16* Ab = A + (size_t)b * sAb + (size_t)m0 * lda;
  const u16* Bb = B + (size_t)b * sBb + (size_t)n0 * ldb;

  // staging segments: A has 16 segs of 16 rows (2 per wave), B has 8 (1/wave)
  const int gsa0 = 2 * wave, gsa1 = 2 * wave + 1;
  const u16* pA0 =
      Ab + (size_t)(((gsa0 >> 3) << 7) + ((gsa0 & 7) << 4) + srow) * lda + scol;
  const u16* pA1 =
      Ab + (size_t)(((gsa1 >> 3) << 7) + ((gsa1 & 7) << 4) + srow) * lda + scol;
  const u16* pB = Bb + (size_t)((wave << 4) + srow) * ldb + scol;
  u16* lA0 = As + gsa0 * 512;
  u16* lA1 = As + gsa1 * 512;
  u16* lB = Bs + wave * 512;

  // fragment base offsets (elements, within current buffer)
  const int aoff = (wm >> 1) * 4096 + (wm & 1) * 2048 + vbase;  // + mf*512
  const int boff = wn * 2048 + vbase;                           // + nf*512

  f32x4 acc[4][4] = {};

#define STAGE3(bufidx, kk)                             \
  {                                                    \
    gload_lds16(pA0 + (kk) * 32, lA0 + (bufidx) * 8192); \
    gload_lds16(pA1 + (kk) * 32, lA1 + (bufidx) * 8192); \
    gload_lds16(pB + (kk) * 32, lB + (bufidx) * 4096);   \
  }

  const int nk = K >> 5;  // BK=32; nk >= 16 for all call sites
  STAGE3(0, 0)
  STAGE3(1, 1)
  int cur = 0;
  for (int kt = 0; kt < nk; ++kt) {
    if (kt + 2 < nk) {
      int stb = cur + 2;
      if (stb >= 3) stb -= 3;
      STAGE3(stb, kt + 2)
      asm volatile("s_waitcnt vmcnt(6)" ::: "memory");  // tile kt landed
    } else if (kt + 1 < nk) {
      asm volatile("s_waitcnt vmcnt(3)" ::: "memory");
    } else {
      asm volatile("s_waitcnt vmcnt(0)" ::: "memory");
    }
    asm volatile("s_barrier" ::: "memory");  // tile kt visible to all waves

    const u16* Asc = As + cur * 8192;
    const u16* Bsc = Bs + cur * 4096;
    bf16x8 bf[4];
#pragma unroll
    for (int nfr = 0; nfr < 4; ++nfr)
      bf[nfr] = *(const bf16x8*)&Bsc[boff + nfr * 512];
    __builtin_amdgcn_s_setprio(1);
#pragma unroll
    for (int mf = 0; mf < 4; ++mf) {
      bf16x8 af = *(const bf16x8*)&Asc[aoff + mf * 512];
#pragma unroll
      for (int nfr = 0; nfr < 4; ++nfr)
        acc[mf][nfr] = __builtin_amdgcn_mfma_f32_16x16x32_bf16(
            af, bf[nfr], acc[mf][nfr], 0, 0, 0);
    }
    __builtin_amdgcn_s_setprio(0);
    // all waves done reading buf `cur` before a later STAGE overwrites it
    asm volatile("s_barrier" ::: "memory");
    if (++cur == 3) cur = 0;
  }
#undef STAGE3

  const float SCALE = 0.044194173824159216f;  // 512^-0.5
#pragma unroll
  for (int mf = 0; mf < 4; ++mf) {
#pragma unroll
    for (int nfr = 0; nfr < 4; ++nfr) {
      int n = n0 + wn * 64 + nfr * 16 + l16;
      float bn = 0.f;
      if constexpr (EPI == 0)
        bn = (n < 512) ? bias[n] : bias2_or_resid[n - 512];
#pragma unroll
      for (int reg = 0; reg < 4; ++reg) {
        int m = m0 + wm * 64 + mf * 16 + quad * 4 + reg;
        float v = acc[mf][nfr][reg];
        size_t idx = (size_t)b * sOb + (size_t)m * ldo + n;
        if constexpr (EPI == 0) {
          ((u16*)Out)[idx] = f2bf(v + bn);
        } else if constexpr (EPI == 1) {
          ((u16*)Out)[idx] = f2bf(v + bias[m]);
        } else if constexpr (EPI == 2) {
          ((u16*)Out)[idx] = f2bf(v * SCALE);
        } else if constexpr (EPI == 3) {
          ((u16*)Out)[idx] = f2bf(v);
        } else {
          ((float*)Out)[idx] =
              v + bias[m] + bias2_or_resid[(size_t)b * sRb + (size_t)m * ldo + n];
        }
      }
    }
  }
}

// ---------------- Softmax over bf16 rows of Sc [nb*S][S], in place ------------
__global__ __launch_bounds__(256) void softmax_kernel(u16* __restrict__ Sc) {
  size_t row = blockIdx.x;
  u16* rp = Sc + row * (size_t)Ssp;
  uint2 u = ((const uint2*)rp)[threadIdx.x];  // 4 bf16
  const u16* ph = (const u16*)&u;
  float v0 = bf2f(ph[0]), v1 = bf2f(ph[1]), v2 = bf2f(ph[2]), v3 = bf2f(ph[3]);
  float mx = fmaxf(fmaxf(v0, v1), fmaxf(v2, v3));
#pragma unroll
  for (int off = 32; off > 0; off >>= 1) mx = fmaxf(mx, __shfl_xor(mx, off));
  __shared__ float sm[4];
  __shared__ float sd[4];
  int wid = threadIdx.x >> 6;
  if ((threadIdx.x & 63) == 0) sm[wid] = mx;
  __syncthreads();  // also: all row reads complete before any write below
  mx = fmaxf(fmaxf(sm[0], sm[1]), fmaxf(sm[2], sm[3]));
  float e0 = __expf(v0 - mx), e1 = __expf(v1 - mx);
  float e2 = __expf(v2 - mx), e3 = __expf(v3 - mx);
  float s = e0 + e1 + e2 + e3;
#pragma unroll
  for (int off = 32; off > 0; off >>= 1) s += __shfl_xor(s, off);
  if ((threadIdx.x & 63) == 0) sd[wid] = s;
  __syncthreads();
  s = sd[0] + sd[1] + sd[2] + sd[3];
  float inv = 1.f / s;
  union { u16 s4[4]; uint2 v2; } pk;
  pk.s4[0] = f2bf(e0 * inv); pk.s4[1] = f2bf(e1 * inv);
  pk.s4[2] = f2bf(e2 * inv); pk.s4[3] = f2bf(e3 * inv);
  ((uint2*)rp)[threadIdx.x] = pk.v2;
}

extern "C" void kernel_launch(void* const* d_in, const int* in_sizes, int n_in,
                              void* d_out, int out_size, void* d_ws, size_t ws_size,
                              hipStream_t stream) {
  (void)in_sizes; (void)n_in; (void)out_size;
  const float* x   = (const float*)d_in[0];
  const float* gns = (const float*)d_in[1];
  const float* gnb = (const float*)d_in[2];
  const float* Wq  = (const float*)d_in[3];
  const float* bq  = (const float*)d_in[4];
  const float* Wk  = (const float*)d_in[5];
  const float* bk  = (const float*)d_in[6];
  const float* Wv  = (const float*)d_in[7];
  const float* bv  = (const float*)d_in[8];
  const float* Wt  = (const float*)d_in[9];
  const float* bt  = (const float*)d_in[10];
  float* out = (float*)d_out;
  char* ws = (char*)d_ws;

  // Workspace:
  //   qkt @ 0MB   (64MB bf16 [b][s][1024], q|k fused) -> o_t aliases its start
  //   v   @ 64MB  (32MB bf16 [b][d][s])
  //   W_t @ 96MB  (4 x 0.5MB bf16 [d][c]: q,k,v,t -> Wq|Wk contiguous = fused N)
  //   stats @98MB (256KB float2)
  //   xt  @ 99MB  (32MB bf16 [b][s][c]) -> dead after projections
  //   Sc  @ 99MB  (NB*2MB bf16, overlays xt; softmax in place)
  const size_t QKSZ = (size_t)Bsz * Ssp * 1024 * 2;  // 64 MB
  u16* qkt = (u16*)ws;
  u16* vv  = (u16*)(ws + QKSZ);
  u16* Wts = (u16*)(ws + (96ull << 20));
  float2* stats = (float2*)(ws + (98ull << 20));
  u16* xt  = (u16*)(ws + (99ull << 20));
  u16* Sc  = xt;
  u16* ot  = qkt;

  int NB;  // batches per score chunk (Sc = NB*2MB @ 99MB); ws_size is constant
  if (ws_size >= (163ull << 20)) NB = 32;
  else if (ws_size >= (131ull << 20)) NB = 16;
  else NB = 8;

  const size_t WSZ = (size_t)Cch * Cch;
  u16* Wvt = Wts + 2 * WSZ;
  u16* Wtt = Wts + 3 * WSZ;

  const size_t sSC  = (size_t)Ssp * Cch;   // xt / o_t per-batch elems
  const size_t sQK  = (size_t)Ssp * 1024;  // qkt per-batch elems
  const size_t sCS  = (size_t)Cch * Ssp;   // v / x / out per-batch elems
  const size_t sScB = (size_t)Ssp * Ssp;   // score per-batch elems (bf16)
  dim3 blk(256);
  dim3 blk8(512);

  gnstats_kernel<<<dim3(Bsz * Grp), blk, 0, stream>>>(x, gns, gnb, stats);
  xpose_gn<<<dim3(Ssp / 64, Cch / 64, Bsz), blk, 0, stream>>>(x, stats, xt);
  wxpose<<<dim3(8, 8, 4), blk, 0, stream>>>(Wq, Wk, Wv, Wt, Wts);

  // Grids: x = N/128, y = M/256, z = batch
  // fused q|k: m=s(1024), n=dq|dk(1024), k=c(512): A=xt, B=Wq_t|Wk_t
  mfma_nt3<0><<<dim3(8, 4, Bsz), blk8, 0, stream>>>(
      xt, sSC, Cch, Wts, 0, Cch, qkt, sQK, 1024, bq, bk, 0, Cch);
  // v: m=d(512), n=s(1024), k=c(512): A=Wv_t, B=xt -> v[d][s] + bias[m]
  mfma_nt3<1><<<dim3(8, 2, Bsz), blk8, 0, stream>>>(
      Wvt, 0, Cch, xt, sSC, Cch, vv, sCS, Ssp, bv, nullptr, 0, Cch);

  for (int b0 = 0; b0 < Bsz; b0 += NB) {
    int nb = (b0 + NB <= Bsz) ? NB : (Bsz - b0);
    // scores: m=s, n=s', k=d: A=q (qkt+0), B=k (qkt+512) -> Sc bf16 * C^-0.5
    mfma_nt3<2><<<dim3(8, 4, nb), blk8, 0, stream>>>(
        qkt + b0 * sQK, sQK, 1024, qkt + b0 * sQK + 512, sQK, 1024,
        Sc, sScB, Ssp, nullptr, nullptr, 0, Cch);
    softmax_kernel<<<dim3(nb * Ssp), blk, 0, stream>>>(Sc);
    // PV: m=s(1024), n=c(512), k=t(1024): A=P bf16, B=v -> o_t[s][c]
    mfma_nt3<3><<<dim3(4, 4, nb), blk8, 0, stream>>>(
        Sc, sScB, Ssp, vv + b0 * sCS, sCS, Ssp,
        ot + b0 * sSC, sSC, Cch, nullptr, nullptr, 0, Ssp);
  }

  // final: m=d(512), n=s(1024), k=c(512): A=Wt_t, B=o_t -> fp32 +bias[m]+x
  mfma_nt3<4><<<dim3(8, 2, Bsz), blk8, 0, stream>>>(
      Wtt, 0, Cch, ot, sSC, Cch, out, sCS, Ssp, bt, x, sCS, Cch);
}

// Round 4
// 355.419 us; speedup vs baseline: 1.0752x; 1.0093x over previous
//
#include <hip/hip_runtime.h>
#include <stdint.h>

// x [B=32, C=512, H=32, W=32] fp32, 32 groups, S = H*W = 1024. All I/O fp32.
// Internal tensors bf16: xt[b][s][c], qkt[b][s][1024] (q|k fused), v[b][d][s],
// Sc/P[b][s][t] bf16, o_t[b][s][c]. All GEMMs NT (Out[m][n] = sum_k A[m][k]B[n][k])
// on mfma_f32_16x16x32_bf16:
//   A-frag: A[m=lane&15][k=quad*8+j]  B-frag: B[n=lane&15][k=quad*8+j]
//   C/D:    col=lane&15, row=quad*4+reg
// R7: bijective XCD-aware block swizzle (T1): scores FETCH 166->49MB.
// R10: m201-style fine-phase 256x256/BK=64 8-wave kernel (mfma_ntf) for ALL
//   GEMMs. R9 post-mortem: lockstep {read-burst -> MFMA-burst} alternates the
//   LDS pipe (1536 cy/CU/iter) and MFMA pipe (1242 cy) instead of overlapping
//   -> both stuck ~25%. Per-wave 128x64 makes MFMA-pipe dominant (LDS:MFMA
//   0.93), and 4 fine phases/K-tile interleave {ds_read || stage || MFMA}:
//   ph0: A m0-3 k0 + B k0 (8 rds) -> mfma m0-3xk0 ; ph1: A m0-3 k1 + B k1 ->
//   mfma k1 ; ph2: A m4-7 k0 (4 rds, B k0 live) ; ph3: A m4-7 k1.
//   Each phase also issues 2 gload_lds for tile t+1 (buf^1). vmcnt(0) only at
//   tile start (loads issued >=3 phases earlier; per-wave wait + barrier makes
//   completion global). lgkmcnt(0)+sched_barrier(0) before MFMA (rule #18).
#define Bsz 32
#define Cch 512
#define Ssp 1024
#define Grp 32
#define CPG 16

typedef unsigned short u16;
typedef __attribute__((ext_vector_type(8))) short bf16x8;
typedef __attribute__((ext_vector_type(4))) float f32x4;

__device__ __forceinline__ float bf2f(u16 u) {
  union { float f; uint32_t i; } w; w.i = ((uint32_t)u) << 16; return w.f;
}
__device__ __forceinline__ u16 f2bf(float f) {
  union { float f; uint32_t i; } w; w.f = f;
  uint32_t r = w.i + 0x7fffu + ((w.i >> 16) & 1u);  // RNE
  return (u16)(r >> 16);
}

__device__ __forceinline__ void gload_lds16(const u16* g, u16* l) {
  __builtin_amdgcn_global_load_lds(
      (const __attribute__((address_space(1))) uint32_t*)g,
      (__attribute__((address_space(3))) uint32_t*)l, 16, 0, 0);
}

// ---------------- GN stats: one block per (b,g) -> per-channel affine (A,B) ----
__global__ __launch_bounds__(256) void gnstats_kernel(
    const float* __restrict__ x, const float* __restrict__ scale,
    const float* __restrict__ bias, float2* __restrict__ stats) {
  int b = blockIdx.x >> 5;
  int g = blockIdx.x & 31;
  size_t base = ((size_t)b * Cch + (size_t)g * CPG) * Ssp;
  const float4* xv = (const float4*)(x + base);

  float sum = 0.f, sumsq = 0.f;
#pragma unroll
  for (int it = 0; it < 16; ++it) {
    float4 v = xv[threadIdx.x + 256 * it];
    sum += (v.x + v.y) + (v.z + v.w);
    sumsq += (v.x * v.x + v.y * v.y) + (v.z * v.z + v.w * v.w);
  }
#pragma unroll
  for (int off = 32; off > 0; off >>= 1) {
    sum += __shfl_xor(sum, off);
    sumsq += __shfl_xor(sumsq, off);
  }
  __shared__ float sm[8];
  int wid = threadIdx.x >> 6;
  if ((threadIdx.x & 63) == 0) { sm[wid] = sum; sm[4 + wid] = sumsq; }
  __syncthreads();
  sum = sm[0] + sm[1] + sm[2] + sm[3];
  sumsq = sm[4] + sm[5] + sm[6] + sm[7];
  float mean = sum * (1.f / 16384.f);
  float var = sumsq * (1.f / 16384.f) - mean * mean;
  float rstd = rsqrtf(var + 1e-6f);
  if (threadIdx.x < CPG) {
    int c = g * CPG + threadIdx.x;
    float sc = scale[c] * rstd;
    stats[(size_t)b * Cch + c] = make_float2(sc, bias[c] - mean * sc);
  }
}

// ---------------- x[b][c][s] fp32 -> xt[b][s][c] bf16 with GN affine ----------
__global__ __launch_bounds__(256) void xpose_gn(
    const float* __restrict__ x, const float2* __restrict__ stats,
    u16* __restrict__ xt) {
  __shared__ float T[64][65];
  int b = blockIdx.z;
  int s0 = blockIdx.x * 64, c0 = blockIdx.y * 64;
  int t = threadIdx.x;
  {
    int tx = t & 15, ty = t >> 4;
    const float* xb = x + ((size_t)b * Cch + c0) * Ssp + s0;
#pragma unroll
    for (int i = 0; i < 4; ++i) {
      int c = ty + 16 * i;
      float2 af = stats[(size_t)b * Cch + c0 + c];
      float4 v = *(const float4*)&xb[(size_t)c * Ssp + tx * 4];
      T[c][tx * 4 + 0] = v.x * af.x + af.y;
      T[c][tx * 4 + 1] = v.y * af.x + af.y;
      T[c][tx * 4 + 2] = v.z * af.x + af.y;
      T[c][tx * 4 + 3] = v.w * af.x + af.y;
    }
  }
  __syncthreads();
  {
    int cx = t & 7, sy = t >> 3;
    u16* ob = xt + ((size_t)b * Ssp + s0) * Cch + c0;
#pragma unroll
    for (int i = 0; i < 2; ++i) {
      int s = sy + 32 * i;
      union { u16 h[8]; uint4 v4; } pk;
#pragma unroll
      for (int j = 0; j < 8; ++j) pk.h[j] = f2bf(T[cx * 8 + j][s]);
      *(uint4*)&ob[(size_t)s * Cch + cx * 8] = pk.v4;
    }
  }
}

// ---------------- W[c][d] fp32 (512x512) -> Wt[d][c] bf16, 4 weights ----------
__global__ __launch_bounds__(256) void wxpose(
    const float* __restrict__ w0, const float* __restrict__ w1,
    const float* __restrict__ w2, const float* __restrict__ w3,
    u16* __restrict__ dst) {
  const float* W = blockIdx.z == 0 ? w0 : blockIdx.z == 1 ? w1
                   : blockIdx.z == 2 ? w2 : w3;
  u16* D = dst + (size_t)blockIdx.z * Cch * Cch;
  __shared__ float T[64][65];
  int d0 = blockIdx.x * 64, c0 = blockIdx.y * 64;
  int t = threadIdx.x;
  {
    int tx = t & 15, ty = t >> 4;
#pragma unroll
    for (int i = 0; i < 4; ++i) {
      int c = ty + 16 * i;
      float4 v = *(const float4*)&W[(size_t)(c0 + c) * Cch + d0 + tx * 4];
      T[c][tx * 4 + 0] = v.x; T[c][tx * 4 + 1] = v.y;
      T[c][tx * 4 + 2] = v.z; T[c][tx * 4 + 3] = v.w;
    }
  }
  __syncthreads();
  {
    int cx = t & 7, dy = t >> 3;
#pragma unroll
    for (int i = 0; i < 2; ++i) {
      int d = dy + 32 * i;
      union { u16 h[8]; uint4 v4; } pk;
#pragma unroll
      for (int j = 0; j < 8; ++j) pk.h[j] = f2bf(T[cx * 8 + j][d]);
      *(uint4*)&D[(size_t)(d0 + d) * Cch + c0 + cx * 8] = pk.v4;
    }
  }
}

// -------- R10: 256x256 BK=64 8-wave fine-phase NT GEMM (all epilogues) --------
// 8 waves 2(M)x4(N); per-wave 128x64 = 8 m-frags x 4 n-frags (32 f32x4 acc).
// LDS per operand: 2 bufs x 32KB; buf = [khalf][16 segs][16rows x 32k unit],
// unit = proven row-pair-XOR layout (pair-line q=r>>1; logical chunk
// c=(r&1)*4+k/8; phys p = c^(q&7); 2-way max bank aliasing = free).
// Staging: 32 units/operand/tile; wave w stages units 4w+p (p=phase) for tile
// t+1 each phase (2 gload_lds/phase). Reads per phase from buf cur.
// EPI 0: bf16 + bias(n<512?bias:b2)  EPI 1: bf16 + bias[m]  EPI 2: bf16 *scale
// EPI 3: bf16                        EPI 4: f32 + bias[m] + resid
template <int EPI>
__global__ __launch_bounds__(512, 2) void mfma_ntf(
    const u16* __restrict__ A, size_t sAb, int lda,
    const u16* __restrict__ B, size_t sBb, int ldb,
    void* __restrict__ Out, size_t sOb, int ldo,
    const float* __restrict__ bias,
    const float* __restrict__ bias2_or_resid, size_t sRb, int K) {
  __shared__ u16 As[2 * 16384];  // 64 KB
  __shared__ u16 Bs[2 * 16384];  // 64 KB

  // bijective XCD-aware swizzle (R7)
  const int nx = gridDim.x, ny = gridDim.y;
  const int pb = nx * ny;
  const int nwg = pb * gridDim.z;
  const int flat = (blockIdx.z * ny + blockIdx.y) * nx + blockIdx.x;
  const int qq = nwg >> 3, rr = nwg & 7;
  const int xcd = flat & 7, lid = flat >> 3;
  const int nf2 = (xcd < rr ? xcd * (qq + 1) : rr * (qq + 1) + (xcd - rr) * qq) + lid;
  const int b = nf2 / pb;
  const int rem = nf2 - b * pb;
  const int m0 = (rem / nx) * 256, n0 = (rem % nx) * 256;

  const int tid = threadIdx.x;
  const int lane = tid & 63, wave = tid >> 6;  // 0..7
  const int wm = wave >> 2, wn = wave & 3;     // 2(M) x 4(N)
  const int quad = lane >> 4, l16 = lane & 15;

  // staging decode (proven): phys chunk p = lane&7 of pair q' = lane>>3 within
  // a 16-row unit; logical c = p ^ q' -> row 2q' + (c>>2), k-off (c&3)*8.
  const int sp = lane & 7, sq = lane >> 3;
  const int scl = sp ^ sq;
  const int srow = 2 * sq + (scl >> 2);
  const int scol = (scl & 3) * 8;

  // fragment-read per-lane offset within a 512-elem unit
  const int vbase =
      ((l16 >> 1) << 6) + ((((l16 & 1) << 2) | quad) ^ (l16 >> 1)) * 8;

  const u16* Ab = A + (size_t)b * sAb + (size_t)m0 * lda;
  const u16* Bb = B + (size_t)b * sBb + (size_t)n0 * ldb;

  f32x4 acc[8][4] = {};

  // stage unit u = 4*wave+p of tile (kt1) into buffer nbuf, both operands
#define STG(p, kt1, nbuf)                                                      \
  {                                                                            \
    const int u_ = wave * 4 + (p);                                             \
    const int su_ = u_ & 15, kh_ = u_ >> 4;                                    \
    gload_lds16(Ab + (size_t)(su_ * 16 + srow) * lda + (kt1) * 64 + kh_ * 32 + \
                    scol,                                                      \
                As + (nbuf) * 16384 + kh_ * 8192 + su_ * 512);                 \
    gload_lds16(Bb + (size_t)(su_ * 16 + srow) * ldb + (kt1) * 64 + kh_ * 32 + \
                    scol,                                                      \
                Bs + (nbuf) * 16384 + kh_ * 8192 + su_ * 512);                 \
  }

  // fragment loads from buf cur
#define LDA(mf, kk) \
  (*(const bf16x8*)&As[cur * 16384 + (kk) * 8192 + (wm * 8 + (mf)) * 512 + vbase])
#define LDB(nf, kk) \
  (*(const bf16x8*)&Bs[cur * 16384 + (kk) * 8192 + (wn * 4 + (nf)) * 512 + vbase])

#define BAR asm volatile("s_barrier" ::: "memory")
#define WAIT_VM0 asm volatile("s_waitcnt vmcnt(0)" ::: "memory")
#define WAIT_LGKM0                                    \
  asm volatile("s_waitcnt lgkmcnt(0)" ::: "memory");  \
  __builtin_amdgcn_sched_barrier(0)

  // prologue: stage tile 0 into buf 0
#pragma unroll
  for (int p = 0; p < 4; ++p) STG(p, 0, 0)

  const int nk = K >> 6;
  bf16x8 b0[4], b1[4], a[4];
  for (int kt = 0; kt < nk; ++kt) {
    const int cur = kt & 1;
    const int nbuf = cur ^ 1;
    const bool nxt = (kt + 1 < nk);
    // ---- ph0: A m0-3 k0 + B k0 -> mfma m0-3 x k0
    WAIT_VM0;  // tile kt landed (own 8 loads, issued >=3 phases ago); then sync
    BAR;       // => ALL waves' tile-kt loads complete; buf cur valid
#pragma unroll
    for (int i = 0; i < 4; ++i) b0[i] = LDB(i, 0);
#pragma unroll
    for (int i = 0; i < 4; ++i) a[i] = LDA(i, 0);
    if (nxt) STG(0, kt + 1, nbuf)
    BAR;
    WAIT_LGKM0;
    __builtin_amdgcn_s_setprio(1);
#pragma unroll
    for (int mf = 0; mf < 4; ++mf)
#pragma unroll
      for (int nf = 0; nf < 4; ++nf)
        acc[mf][nf] = __builtin_amdgcn_mfma_f32_16x16x32_bf16(
            a[mf], b0[nf], acc[mf][nf], 0, 0, 0);
    __builtin_amdgcn_s_setprio(0);
    // ---- ph1: A m0-3 k1 + B k1 -> mfma m0-3 x k1
#pragma unroll
    for (int i = 0; i < 4; ++i) b1[i] = LDB(i, 1);
#pragma unroll
    for (int i = 0; i < 4; ++i) a[i] = LDA(i, 1);
    if (nxt) STG(1, kt + 1, nbuf)
    BAR;
    WAIT_LGKM0;
    __builtin_amdgcn_s_setprio(1);
#pragma unroll
    for (int mf = 0; mf < 4; ++mf)
#pragma unroll
      for (int nf = 0; nf < 4; ++nf)
        acc[mf][nf] = __builtin_amdgcn_mfma_f32_16x16x32_bf16(
            a[mf], b1[nf], acc[mf][nf], 0, 0, 0);
    __builtin_amdgcn_s_setprio(0);
    // ---- ph2: A m4-7 k0 (B k0 live) -> mfma m4-7 x k0
#pragma unroll
    for (int i = 0; i < 4; ++i) a[i] = LDA(4 + i, 0);
    if (nxt) STG(2, kt + 1, nbuf)
    BAR;
    WAIT_LGKM0;
    __builtin_amdgcn_s_setprio(1);
#pragma unroll
    for (int mf = 0; mf < 4; ++mf)
#pragma unroll
      for (int nf = 0; nf < 4; ++nf)
        acc[4 + mf][nf] = __builtin_amdgcn_mfma_f32_16x16x32_bf16(
            a[mf], b0[nf], acc[4 + mf][nf], 0, 0, 0);
    __builtin_amdgcn_s_setprio(0);
    // ---- ph3: A m4-7 k1 (B k1 live) -> mfma m4-7 x k1
#pragma unroll
    for (int i = 0; i < 4; ++i) a[i] = LDA(4 + i, 1);
    if (nxt) STG(3, kt + 1, nbuf)
    BAR;
    WAIT_LGKM0;
    __builtin_amdgcn_s_setprio(1);
#pragma unroll
    for (int mf = 0; mf < 4; ++mf)
#pragma unroll
      for (int nf = 0; nf < 4; ++nf)
        acc[4 + mf][nf] = __builtin_amdgcn_mfma_f32_16x16x32_bf16(
            a[mf], b1[nf], acc[4 + mf][nf], 0, 0, 0);
    __builtin_amdgcn_s_setprio(0);
  }
#undef STG
#undef LDA
#undef LDB

  const float SCALE = 0.044194173824159216f;  // 512^-0.5
#pragma unroll
  for (int mf = 0; mf < 8; ++mf) {
#pragma unroll
    for (int nf = 0; nf < 4; ++nf) {
      int n = n0 + wn * 64 + nf * 16 + l16;
      float bn = 0.f;
      if constexpr (EPI == 0)
        bn = (n < 512) ? bias[n] : bias2_or_resid[n - 512];
#pragma unroll
      for (int reg = 0; reg < 4; ++reg) {
        int m = m0 + wm * 128 + mf * 16 + quad * 4 + reg;
        float v = acc[mf][nf][reg];
        size_t idx = (size_t)b * sOb + (size_t)m * ldo + n;
        if constexpr (EPI == 0) {
          ((u16*)Out)[idx] = f2bf(v + bn);
        } else if constexpr (EPI == 1) {
          ((u16*)Out)[idx] = f2bf(v + bias[m]);
        } else if constexpr (EPI == 2) {
          ((u16*)Out)[idx] = f2bf(v * SCALE);
        } else if constexpr (EPI == 3) {
          ((u16*)Out)[idx] = f2bf(v);
        } else {
          ((float*)Out)[idx] =
              v + bias[m] + bias2_or_resid[(size_t)b * sRb + (size_t)m * ldo + n];
        }
      }
    }
  }
}

// ---------------- Softmax over bf16 rows of Sc [nb*S][S], in place ------------
__global__ __launch_bounds__(256) void softmax_kernel(u16* __restrict__ Sc) {
  size_t row = blockIdx.x;
  u16* rp = Sc + row * (size_t)Ssp;
  uint2 u = ((const uint2*)rp)[threadIdx.x];  // 4 bf16
  const u16* ph = (const u16*)&u;
  float v0 = bf2f(ph[0]), v1 = bf2f(ph[1]), v2 = bf2f(ph[2]), v3 = bf2f(ph[3]);
  float mx = fmaxf(fmaxf(v0, v1), fmaxf(v2, v3));
#pragma unroll
  for (int off = 32; off > 0; off >>= 1) mx = fmaxf(mx, __shfl_xor(mx, off));
  __shared__ float sm[4];
  __shared__ float sd[4];
  int wid = threadIdx.x >> 6;
  if ((threadIdx.x & 63) == 0) sm[wid] = mx;
  __syncthreads();  // also: all row reads complete before any write below
  mx = fmaxf(fmaxf(sm[0], sm[1]), fmaxf(sm[2], sm[3]));
  float e0 = __expf(v0 - mx), e1 = __expf(v1 - mx);
  float e2 = __expf(v2 - mx), e3 = __expf(v3 - mx);
  float s = e0 + e1 + e2 + e3;
#pragma unroll
  for (int off = 32; off > 0; off >>= 1) s += __shfl_xor(s, off);
  if ((threadIdx.x & 63) == 0) sd[wid] = s;
  __syncthreads();
  s = sd[0] + sd[1] + sd[2] + sd[3];
  float inv = 1.f / s;
  union { u16 s4[4]; uint2 v2; } pk;
  pk.s4[0] = f2bf(e0 * inv); pk.s4[1] = f2bf(e1 * inv);
  pk.s4[2] = f2bf(e2 * inv); pk.s4[3] = f2bf(e3 * inv);
  ((uint2*)rp)[threadIdx.x] = pk.v2;
}

extern "C" void kernel_launch(void* const* d_in, const int* in_sizes, int n_in,
                              void* d_out, int out_size, void* d_ws, size_t ws_size,
                              hipStream_t stream) {
  (void)in_sizes; (void)n_in; (void)out_size;
  const float* x   = (const float*)d_in[0];
  const float* gns = (const float*)d_in[1];
  const float* gnb = (const float*)d_in[2];
  const float* Wq  = (const float*)d_in[3];
  const float* bq  = (const float*)d_in[4];
  const float* Wk  = (const float*)d_in[5];
  const float* bk  = (const float*)d_in[6];
  const float* Wv  = (const float*)d_in[7];
  const float* bv  = (const float*)d_in[8];
  const float* Wt  = (const float*)d_in[9];
  const float* bt  = (const float*)d_in[10];
  float* out = (float*)d_out;
  char* ws = (char*)d_ws;

  // Workspace:
  //   qkt @ 0MB   (64MB bf16 [b][s][1024], q|k fused) -> o_t aliases its start
  //   v   @ 64MB  (32MB bf16 [b][d][s])
  //   W_t @ 96MB  (4 x 0.5MB bf16 [d][c]: q,k,v,t -> Wq|Wk contiguous = fused N)
  //   stats @98MB (256KB float2)
  //   xt  @ 99MB  (32MB bf16 [b][s][c]) -> dead after projections
  //   Sc  @ 99MB  (NB*2MB bf16, overlays xt; softmax in place)
  const size_t QKSZ = (size_t)Bsz * Ssp * 1024 * 2;  // 64 MB
  u16* qkt = (u16*)ws;
  u16* vv  = (u16*)(ws + QKSZ);
  u16* Wts = (u16*)(ws + (96ull << 20));
  float2* stats = (float2*)(ws + (98ull << 20));
  u16* xt  = (u16*)(ws + (99ull << 20));
  u16* Sc  = xt;
  u16* ot  = qkt;

  int NB;  // batches per score chunk (Sc = NB*2MB @ 99MB); ws_size is constant
  if (ws_size >= (163ull << 20)) NB = 32;
  else if (ws_size >= (131ull << 20)) NB = 16;
  else NB = 8;

  const size_t WSZ = (size_t)Cch * Cch;
  u16* Wvt = Wts + 2 * WSZ;
  u16* Wtt = Wts + 3 * WSZ;

  const size_t sSC  = (size_t)Ssp * Cch;   // xt / o_t per-batch elems
  const size_t sQK  = (size_t)Ssp * 1024;  // qkt per-batch elems
  const size_t sCS  = (size_t)Cch * Ssp;   // v / x / out per-batch elems
  const size_t sScB = (size_t)Ssp * Ssp;   // score per-batch elems (bf16)
  dim3 blk(256);
  dim3 blk8(512);

  gnstats_kernel<<<dim3(Bsz * Grp), blk, 0, stream>>>(x, gns, gnb, stats);
  xpose_gn<<<dim3(Ssp / 64, Cch / 64, Bsz), blk, 0, stream>>>(x, stats, xt);
  wxpose<<<dim3(8, 8, 4), blk, 0, stream>>>(Wq, Wk, Wv, Wt, Wts);

  // Grids: x = N/256, y = M/256, z = batch
  // fused q|k: m=s(1024), n=dq|dk(1024), k=c(512): A=xt, B=Wq_t|Wk_t
  mfma_ntf<0><<<dim3(4, 4, Bsz), blk8, 0, stream>>>(
      xt, sSC, Cch, Wts, 0, Cch, qkt, sQK, 1024, bq, bk, 0, Cch);
  // v: m=d(512), n=s(1024), k=c(512): A=Wv_t, B=xt -> v[d][s] + bias[m]
  mfma_ntf<1><<<dim3(4, 2, Bsz), blk8, 0, stream>>>(
      Wvt, 0, Cch, xt, sSC, Cch, vv, sCS, Ssp, bv, nullptr, 0, Cch);

  for (int b0 = 0; b0 < Bsz; b0 += NB) {
    int nb = (b0 + NB <= Bsz) ? NB : (Bsz - b0);
    // scores: m=s, n=s', k=d: A=q (qkt+0), B=k (qkt+512) -> Sc bf16 * C^-0.5
    mfma_ntf<2><<<dim3(4, 4, nb), blk8, 0, stream>>>(
        qkt + b0 * sQK, sQK, 1024, qkt + b0 * sQK + 512, sQK, 1024,
        Sc, sScB, Ssp, nullptr, nullptr, 0, Cch);
    softmax_kernel<<<dim3(nb * Ssp), blk, 0, stream>>>(Sc);
    // PV: m=s(1024), n=c(512), k=t(1024): A=P bf16, B=v -> o_t[s][c]
    mfma_ntf<3><<<dim3(2, 4, nb), blk8, 0, stream>>>(
        Sc, sScB, Ssp, vv + b0 * sCS, sCS, Ssp,
        ot + b0 * sSC, sSC, Cch, nullptr, nullptr, 0, Ssp);
  }

  // final: m=d(512), n=s(1024), k=c(512): A=Wt_t, B=o_t -> fp32 +bias[m]+x
  mfma_ntf<4><<<dim3(4, 2, Bsz), blk8, 0, stream>>>(
      Wtt, 0, Cch, ot, sSC, Cch, out, sCS, Ssp, bt, x, sCS, Cch);
}